// Round 1
// baseline (2475.675 us; speedup 1.0000x reference)
//
#include <hip/hip_runtime.h>
#include <math.h>

#define N_NODES 50000
#define N_EDGES 800000
#define DIM 64
#define HID 128
#define LAYERS 3
#define NGRAPH 128

// ---------------------------------------------------------------------------
// scatter-add: agg[dst[e]] += x[src[e]]  (one thread per edge x 4-col group)
// ---------------------------------------------------------------------------
__global__ void scatter_add_kernel(const float* __restrict__ x,
                                   const int* __restrict__ src,
                                   const int* __restrict__ dst,
                                   float* __restrict__ agg) {
    int idx = blockIdx.x * blockDim.x + threadIdx.x;
    int e = idx >> 4;          // 16 float4 groups per 64-wide row
    int j = idx & 15;
    if (e >= N_EDGES) return;
    int s = src[e];
    int d = dst[e];
    const float4 v = *reinterpret_cast<const float4*>(x + (size_t)s * DIM + j * 4);
    float* p = agg + (size_t)d * DIM + j * 4;
    atomicAdd(p + 0, v.x);
    atomicAdd(p + 1, v.y);
    atomicAdd(p + 2, v.z);
    atomicAdd(p + 3, v.w);
}

// ---------------------------------------------------------------------------
// fused GEMM + bias + tanh:  out = tanh((A0 [+ A1]) @ W + b)   [double tanh opt]
// A: [N][K], W: [K][C], out: [N][C]
// block: 256 threads, 64 rows; thread (ty,tx): 4 rows x (C/16) cols
// ---------------------------------------------------------------------------
template<int K, int C, bool TWO_IN, bool DTANH>
__global__ void gemm_act_kernel(const float* __restrict__ A0,
                                const float* __restrict__ A1,
                                const float* __restrict__ W,
                                const float* __restrict__ bias,
                                float* __restrict__ out) {
    constexpr int RB = 64;        // rows per block
    constexpr int KC = 32;        // k chunk
    constexpr int CPT = C / 16;   // cols per thread (8 or 4)
    __shared__ float Alds[KC][RB + 4];   // transposed, padded (stride 68 -> 16B aligned, banks spread)
    __shared__ float Wlds[KC][C];

    const int tid = threadIdx.x;
    const int ty = tid >> 4;      // 0..15
    const int tx = tid & 15;      // 0..15
    const int rb = blockIdx.x * RB;
    const int row0 = ty * 4;
    const int c0 = tx * CPT;

    float acc[4][CPT];
#pragma unroll
    for (int r = 0; r < 4; ++r)
#pragma unroll
        for (int c = 0; c < CPT; ++c) acc[r][c] = 0.f;

    for (int kc = 0; kc < K; kc += KC) {
        // ---- stage A chunk (transposed) ----
        {
            int r = tid >> 2;             // 0..63
            int kq = (tid & 3) * 4;       // 0,4,8,12
            int grow = rb + r;
#pragma unroll
            for (int half = 0; half < 2; ++half) {
                int k0 = kq + half * 16;
                float4 v = make_float4(0.f, 0.f, 0.f, 0.f);
                if (grow < N_NODES) {
                    v = *reinterpret_cast<const float4*>(A0 + (size_t)grow * K + kc + k0);
                    if (TWO_IN) {
                        float4 u = *reinterpret_cast<const float4*>(A1 + (size_t)grow * K + kc + k0);
                        v.x += u.x; v.y += u.y; v.z += u.z; v.w += u.w;
                    }
                }
                Alds[k0 + 0][r] = v.x;
                Alds[k0 + 1][r] = v.y;
                Alds[k0 + 2][r] = v.z;
                Alds[k0 + 3][r] = v.w;
            }
        }
        // ---- stage W chunk ----
        {
            constexpr int PER = (KC * C) / (256 * 4);   // float4 per thread
            const float4* Wg = reinterpret_cast<const float4*>(W + (size_t)kc * C);
            float4* Wl = reinterpret_cast<float4*>(&Wlds[0][0]);
#pragma unroll
            for (int i = 0; i < PER; ++i)
                Wl[tid + i * 256] = Wg[tid + i * 256];
        }
        __syncthreads();
        // ---- compute ----
#pragma unroll
        for (int k = 0; k < KC; ++k) {
            float4 a = *reinterpret_cast<const float4*>(&Alds[k][row0]);
            float av[4] = {a.x, a.y, a.z, a.w};
            float w[CPT];
#pragma unroll
            for (int c = 0; c < CPT; ++c) w[c] = Wlds[k][c0 + c];
#pragma unroll
            for (int r = 0; r < 4; ++r)
#pragma unroll
                for (int c = 0; c < CPT; ++c)
                    acc[r][c] = fmaf(av[r], w[c], acc[r][c]);
        }
        __syncthreads();
    }

    // ---- epilogue: bias + tanh (+tanh) + store ----
    float bv[CPT];
#pragma unroll
    for (int c = 0; c < CPT; ++c) bv[c] = bias[c0 + c];
#pragma unroll
    for (int r = 0; r < 4; ++r) {
        int grow = rb + row0 + r;
        if (grow >= N_NODES) continue;
#pragma unroll
        for (int c = 0; c < CPT; ++c) {
            float v = tanhf(acc[r][c] + bv[c]);
            if (DTANH) v = tanhf(v);
            out[(size_t)grow * C + c0 + c] = v;
        }
    }
}

// ---------------------------------------------------------------------------
// mean pool over sorted graph ids: out[g][d] = mean_{i: batch[i]==g} x[i][d]
// block = graph, thread = channel; range via binary search (batch is sorted)
// ---------------------------------------------------------------------------
__global__ void pool_mean_kernel(const float* __restrict__ x,
                                 const int* __restrict__ batch,
                                 float* __restrict__ out) {
    int g = blockIdx.x;
    int d = threadIdx.x;
    // lower_bound(g)
    int lo = 0, hi = N_NODES;
    while (lo < hi) { int m = (lo + hi) >> 1; if (batch[m] < g) lo = m + 1; else hi = m; }
    int start = lo;
    // lower_bound(g+1)
    hi = N_NODES;
    while (lo < hi) { int m = (lo + hi) >> 1; if (batch[m] < g + 1) lo = m + 1; else hi = m; }
    int end = lo;
    float s = 0.f;
    for (int i = start; i < end; ++i) s += x[(size_t)i * DIM + d];
    float cnt = (float)(end - start);
    out[g * DIM + d] = s / fmaxf(cnt, 1.f);
}

// ---------------------------------------------------------------------------
extern "C" void kernel_launch(void* const* d_in, const int* in_sizes, int n_in,
                              void* d_out, int out_size, void* d_ws, size_t ws_size,
                              hipStream_t stream) {
    const float* attrs = (const float*)d_in[0];
    const float* W1    = (const float*)d_in[1];
    const float* b1    = (const float*)d_in[2];
    const float* W2    = (const float*)d_in[3];
    const float* b2    = (const float*)d_in[4];
    const float* W3    = (const float*)d_in[5];
    const float* b3    = (const float*)d_in[6];
    const int* edge_index = (const int*)d_in[7];
    const int* batch      = (const int*)d_in[8];
    float* out = (float*)d_out;

    float* ws   = (float*)d_ws;
    float* xbuf = ws;                                   // N*D
    float* agg  = xbuf + (size_t)N_NODES * DIM;         // N*D
    float* h1   = agg  + (size_t)N_NODES * DIM;         // N*H
    float* h2   = h1   + (size_t)N_NODES * HID;         // N*H

    const int* src = edge_index;
    const int* dst = edge_index + N_EDGES;

    const int gemm_blocks = (N_NODES + 63) / 64;
    const int scatter_threads = N_EDGES * 16;
    const int scatter_blocks = (scatter_threads + 255) / 256;

    for (int l = 0; l < LAYERS; ++l) {
        const float* x = (l == 0) ? attrs : xbuf;
        hipMemsetAsync(agg, 0, (size_t)N_NODES * DIM * sizeof(float), stream);
        scatter_add_kernel<<<scatter_blocks, 256, 0, stream>>>(x, src, dst, agg);
        gemm_act_kernel<DIM, HID, true, false><<<gemm_blocks, 256, 0, stream>>>(
            x, agg, W1 + (size_t)l * DIM * HID, b1 + (size_t)l * HID, h1);
        gemm_act_kernel<HID, HID, false, false><<<gemm_blocks, 256, 0, stream>>>(
            h1, nullptr, W2 + (size_t)l * HID * HID, b2 + (size_t)l * HID, h2);
        gemm_act_kernel<HID, DIM, false, true><<<gemm_blocks, 256, 0, stream>>>(
            h2, nullptr, W3 + (size_t)l * HID * DIM, b3 + (size_t)l * DIM, xbuf);
    }
    pool_mean_kernel<<<NGRAPH, DIM, 0, stream>>>(xbuf, batch, out);
}

// Round 2
// 730.008 us; speedup vs baseline: 3.3913x; 3.3913x over previous
//
#include <hip/hip_runtime.h>
#include <math.h>

#define N_NODES 50000
#define N_EDGES 800000
#define DIM 64
#define HID 128
#define LAYERS 3
#define NGRAPH 128

// ---------------------------------------------------------------------------
// CSR build: histogram of dst
// ---------------------------------------------------------------------------
__global__ void count_kernel(const int* __restrict__ dst, int* __restrict__ counts) {
    int e = blockIdx.x * blockDim.x + threadIdx.x;
    if (e >= N_EDGES) return;
    atomicAdd(&counts[dst[e]], 1);
}

// single-block exclusive scan over N_NODES counts -> offsets[N+1], cursor[N]
__global__ void scan_kernel(const int* __restrict__ counts,
                            int* __restrict__ offsets,
                            int* __restrict__ cursor) {
    __shared__ int sums[1024];
    const int tid = threadIdx.x;
    constexpr int CH = (N_NODES + 1023) / 1024;   // 49
    const int base = tid * CH;
    int s = 0;
    for (int i = 0; i < CH; ++i) {
        int idx = base + i;
        if (idx < N_NODES) s += counts[idx];
    }
    sums[tid] = s;
    __syncthreads();
    // inclusive Hillis-Steele scan
    for (int off = 1; off < 1024; off <<= 1) {
        int v = (tid >= off) ? sums[tid - off] : 0;
        __syncthreads();
        sums[tid] += v;
        __syncthreads();
    }
    int run = (tid == 0) ? 0 : sums[tid - 1];
    for (int i = 0; i < CH; ++i) {
        int idx = base + i;
        if (idx < N_NODES) {
            offsets[idx] = run;
            cursor[idx]  = run;
            run += counts[idx];
        }
    }
    if (tid == 1023) offsets[N_NODES] = sums[1023];   // == N_EDGES
}

// place each edge's src into its dst's CSR slot
__global__ void place_kernel(const int* __restrict__ src,
                             const int* __restrict__ dst,
                             int* __restrict__ cursor,
                             int* __restrict__ csr_src) {
    int e = blockIdx.x * blockDim.x + threadIdx.x;
    if (e >= N_EDGES) return;
    int pos = atomicAdd(&cursor[dst[e]], 1);
    csr_src[pos] = src[e];
}

// ---------------------------------------------------------------------------
// gather aggregation: agg[i] = sum over incoming edges of x[src]
// 16 lanes per node, each lane owns a float4 column group
// ---------------------------------------------------------------------------
__global__ void gather_kernel(const float* __restrict__ x,
                              const int* __restrict__ offsets,
                              const int* __restrict__ csr_src,
                              float* __restrict__ agg) {
    int idx = blockIdx.x * blockDim.x + threadIdx.x;
    int node = idx >> 4;
    int lane = idx & 15;
    if (node >= N_NODES) return;
    int p   = offsets[node];
    int end = offsets[node + 1];
    float4 acc = make_float4(0.f, 0.f, 0.f, 0.f);
    for (; p < end; ++p) {
        int s = csr_src[p];
        float4 v = *reinterpret_cast<const float4*>(x + (size_t)s * DIM + lane * 4);
        acc.x += v.x; acc.y += v.y; acc.z += v.z; acc.w += v.w;
    }
    *reinterpret_cast<float4*>(agg + (size_t)node * DIM + lane * 4) = acc;
}

// ---------------------------------------------------------------------------
// fused GEMM + bias + tanh:  out = tanh((A0 [+ A1]) @ W + b)   [double tanh opt]
// ---------------------------------------------------------------------------
template<int K, int C, bool TWO_IN, bool DTANH>
__global__ void gemm_act_kernel(const float* __restrict__ A0,
                                const float* __restrict__ A1,
                                const float* __restrict__ W,
                                const float* __restrict__ bias,
                                float* __restrict__ out) {
    constexpr int RB = 64;
    constexpr int KC = 32;
    constexpr int CPT = C / 16;
    __shared__ float Alds[KC][RB + 4];
    __shared__ float Wlds[KC][C];

    const int tid = threadIdx.x;
    const int ty = tid >> 4;
    const int tx = tid & 15;
    const int rb = blockIdx.x * RB;
    const int row0 = ty * 4;
    const int c0 = tx * CPT;

    float acc[4][CPT];
#pragma unroll
    for (int r = 0; r < 4; ++r)
#pragma unroll
        for (int c = 0; c < CPT; ++c) acc[r][c] = 0.f;

    for (int kc = 0; kc < K; kc += KC) {
        {
            int r = tid >> 2;
            int kq = (tid & 3) * 4;
            int grow = rb + r;
#pragma unroll
            for (int half = 0; half < 2; ++half) {
                int k0 = kq + half * 16;
                float4 v = make_float4(0.f, 0.f, 0.f, 0.f);
                if (grow < N_NODES) {
                    v = *reinterpret_cast<const float4*>(A0 + (size_t)grow * K + kc + k0);
                    if (TWO_IN) {
                        float4 u = *reinterpret_cast<const float4*>(A1 + (size_t)grow * K + kc + k0);
                        v.x += u.x; v.y += u.y; v.z += u.z; v.w += u.w;
                    }
                }
                Alds[k0 + 0][r] = v.x;
                Alds[k0 + 1][r] = v.y;
                Alds[k0 + 2][r] = v.z;
                Alds[k0 + 3][r] = v.w;
            }
        }
        {
            constexpr int PER = (KC * C) / (256 * 4);
            const float4* Wg = reinterpret_cast<const float4*>(W + (size_t)kc * C);
            float4* Wl = reinterpret_cast<float4*>(&Wlds[0][0]);
#pragma unroll
            for (int i = 0; i < PER; ++i)
                Wl[tid + i * 256] = Wg[tid + i * 256];
        }
        __syncthreads();
#pragma unroll
        for (int k = 0; k < KC; ++k) {
            float4 a = *reinterpret_cast<const float4*>(&Alds[k][row0]);
            float av[4] = {a.x, a.y, a.z, a.w};
            float w[CPT];
#pragma unroll
            for (int c = 0; c < CPT; ++c) w[c] = Wlds[k][c0 + c];
#pragma unroll
            for (int r = 0; r < 4; ++r)
#pragma unroll
                for (int c = 0; c < CPT; ++c)
                    acc[r][c] = fmaf(av[r], w[c], acc[r][c]);
        }
        __syncthreads();
    }

    float bv[CPT];
#pragma unroll
    for (int c = 0; c < CPT; ++c) bv[c] = bias[c0 + c];
#pragma unroll
    for (int r = 0; r < 4; ++r) {
        int grow = rb + row0 + r;
        if (grow >= N_NODES) continue;
#pragma unroll
        for (int c = 0; c < CPT; ++c) {
            float v = tanhf(acc[r][c] + bv[c]);
            if (DTANH) v = tanhf(v);
            out[(size_t)grow * C + c0 + c] = v;
        }
    }
}

// ---------------------------------------------------------------------------
// mean pool over sorted graph ids
// ---------------------------------------------------------------------------
__global__ void pool_mean_kernel(const float* __restrict__ x,
                                 const int* __restrict__ batch,
                                 float* __restrict__ out) {
    int g = blockIdx.x;
    int d = threadIdx.x;
    int lo = 0, hi = N_NODES;
    while (lo < hi) { int m = (lo + hi) >> 1; if (batch[m] < g) lo = m + 1; else hi = m; }
    int start = lo;
    hi = N_NODES;
    while (lo < hi) { int m = (lo + hi) >> 1; if (batch[m] < g + 1) lo = m + 1; else hi = m; }
    int end = lo;
    float s = 0.f;
    for (int i = start; i < end; ++i) s += x[(size_t)i * DIM + d];
    float cnt = (float)(end - start);
    out[g * DIM + d] = s / fmaxf(cnt, 1.f);
}

// ---------------------------------------------------------------------------
extern "C" void kernel_launch(void* const* d_in, const int* in_sizes, int n_in,
                              void* d_out, int out_size, void* d_ws, size_t ws_size,
                              hipStream_t stream) {
    const float* attrs = (const float*)d_in[0];
    const float* W1    = (const float*)d_in[1];
    const float* b1    = (const float*)d_in[2];
    const float* W2    = (const float*)d_in[3];
    const float* b2    = (const float*)d_in[4];
    const float* W3    = (const float*)d_in[5];
    const float* b3    = (const float*)d_in[6];
    const int* edge_index = (const int*)d_in[7];
    const int* batch      = (const int*)d_in[8];
    float* out = (float*)d_out;

    float* ws   = (float*)d_ws;
    float* xbuf = ws;                                   // N*D
    float* agg  = xbuf + (size_t)N_NODES * DIM;         // N*D
    float* h1   = agg  + (size_t)N_NODES * DIM;         // N*H
    float* h2   = h1   + (size_t)N_NODES * HID;         // N*H
    int* offsets = (int*)(h2 + (size_t)N_NODES * HID);  // N+1
    int* csr_src = offsets + N_NODES + 1;               // E
    // build-time scratch aliased into h1 (h1 not live until first GEMM)
    int* counts  = (int*)h1;                            // N
    int* cursor  = counts + N_NODES;                    // N

    const int* src = edge_index;
    const int* dst = edge_index + N_EDGES;

    const int gemm_blocks = (N_NODES + 63) / 64;
    const int edge_blocks = (N_EDGES + 255) / 256;
    const int gather_blocks = (N_NODES * 16 + 255) / 256;

    // ---- CSR build (once; edge list is layer-invariant) ----
    hipMemsetAsync(counts, 0, (size_t)N_NODES * sizeof(int), stream);
    count_kernel<<<edge_blocks, 256, 0, stream>>>(dst, counts);
    scan_kernel<<<1, 1024, 0, stream>>>(counts, offsets, cursor);
    place_kernel<<<edge_blocks, 256, 0, stream>>>(src, dst, cursor, csr_src);

    for (int l = 0; l < LAYERS; ++l) {
        const float* x = (l == 0) ? attrs : xbuf;
        gather_kernel<<<gather_blocks, 256, 0, stream>>>(x, offsets, csr_src, agg);
        gemm_act_kernel<DIM, HID, true, false><<<gemm_blocks, 256, 0, stream>>>(
            x, agg, W1 + (size_t)l * DIM * HID, b1 + (size_t)l * HID, h1);
        gemm_act_kernel<HID, HID, false, false><<<gemm_blocks, 256, 0, stream>>>(
            h1, nullptr, W2 + (size_t)l * HID * HID, b2 + (size_t)l * HID, h2);
        gemm_act_kernel<HID, DIM, false, true><<<gemm_blocks, 256, 0, stream>>>(
            h2, nullptr, W3 + (size_t)l * HID * DIM, b3 + (size_t)l * DIM, xbuf);
    }
    pool_mean_kernel<<<NGRAPH, DIM, 0, stream>>>(xbuf, batch, out);
}

// Round 3
// 617.718 us; speedup vs baseline: 4.0078x; 1.1818x over previous
//
#include <hip/hip_runtime.h>
#include <math.h>

#define N_NODES 50000
#define N_EDGES 800000
#define DIM 64
#define HID 128
#define LAYERS 3
#define NGRAPH 128

#define SCAN_TILE 1024
#define SCAN_NB ((N_NODES + SCAN_TILE - 1) / SCAN_TILE)   // 49

// ---------------------------------------------------------------------------
// CSR build: histogram of dst
// ---------------------------------------------------------------------------
__global__ void count_kernel(const int* __restrict__ dst, int* __restrict__ counts) {
    int e = blockIdx.x * blockDim.x + threadIdx.x;
    if (e >= N_EDGES) return;
    atomicAdd(&counts[dst[e]], 1);
}

// ---- hierarchical scan: (1) per-block reduce ----
__global__ void scan_partial_kernel(const int* __restrict__ counts,
                                    int* __restrict__ bsum) {
    __shared__ int red[256];
    const int b = blockIdx.x, tid = threadIdx.x;
    const int base = b * SCAN_TILE + tid * 4;
    int s = 0;
    if (base + 3 < N_NODES) {
        int4 v = *reinterpret_cast<const int4*>(counts + base);
        s = v.x + v.y + v.z + v.w;
    } else {
        for (int i = 0; i < 4; ++i)
            if (base + i < N_NODES) s += counts[base + i];
    }
    red[tid] = s;
    __syncthreads();
    for (int off = 128; off > 0; off >>= 1) {
        if (tid < off) red[tid] += red[tid + off];
        __syncthreads();
    }
    if (tid == 0) bsum[b] = red[0];
}

// ---- (2) scan the 49 block sums in one wave ----
__global__ void scan_mid_kernel(const int* __restrict__ bsum,
                                int* __restrict__ bpre,
                                int* __restrict__ offsets) {
    int tid = threadIdx.x;   // 64 threads, one wave
    int orig = (tid < SCAN_NB) ? bsum[tid] : 0;
    int v = orig;
    for (int off = 1; off < 64; off <<= 1) {
        int u = __shfl_up(v, off);
        if (tid >= off) v += u;
    }
    if (tid < SCAN_NB) bpre[tid] = v - orig;   // exclusive prefix
    if (tid == 0) offsets[N_NODES] = N_EDGES;
}

// ---- (3) per-block local scan + write offsets/cursor ----
__global__ void scan_final_kernel(const int* __restrict__ counts,
                                  const int* __restrict__ bpre,
                                  int* __restrict__ offsets,
                                  int* __restrict__ cursor) {
    __shared__ int pre[256];
    const int b = blockIdx.x, tid = threadIdx.x;
    const int base = b * SCAN_TILE + tid * 4;
    int c[4];
    int s = 0;
#pragma unroll
    for (int i = 0; i < 4; ++i) {
        c[i] = (base + i < N_NODES) ? counts[base + i] : 0;
        s += c[i];
    }
    pre[tid] = s;
    __syncthreads();
    for (int off = 1; off < 256; off <<= 1) {
        int v = (tid >= off) ? pre[tid - off] : 0;
        __syncthreads();
        pre[tid] += v;
        __syncthreads();
    }
    int run = bpre[b] + pre[tid] - s;   // exclusive across whole array
#pragma unroll
    for (int i = 0; i < 4; ++i) {
        if (base + i < N_NODES) {
            offsets[base + i] = run;
            cursor[base + i]  = run;
            run += c[i];
        }
    }
}

// place each edge's src into its dst's CSR slot
__global__ void place_kernel(const int* __restrict__ src,
                             const int* __restrict__ dst,
                             int* __restrict__ cursor,
                             int* __restrict__ csr_src) {
    int e = blockIdx.x * blockDim.x + threadIdx.x;
    if (e >= N_EDGES) return;
    int pos = atomicAdd(&cursor[dst[e]], 1);
    csr_src[pos] = src[e];
}

// ---------------------------------------------------------------------------
// gather aggregation: agg[i] = sum over incoming edges of x[src]
// ---------------------------------------------------------------------------
__global__ void gather_kernel(const float* __restrict__ x,
                              const int* __restrict__ offsets,
                              const int* __restrict__ csr_src,
                              float* __restrict__ agg) {
    int idx = blockIdx.x * blockDim.x + threadIdx.x;
    int node = idx >> 4;
    int lane = idx & 15;
    if (node >= N_NODES) return;
    int p   = offsets[node];
    int end = offsets[node + 1];
    float4 acc = make_float4(0.f, 0.f, 0.f, 0.f);
    for (; p < end; ++p) {
        int s = csr_src[p];
        float4 v = *reinterpret_cast<const float4*>(x + (size_t)s * DIM + lane * 4);
        acc.x += v.x; acc.y += v.y; acc.z += v.z; acc.w += v.w;
    }
    *reinterpret_cast<float4*>(agg + (size_t)node * DIM + lane * 4) = acc;
}

// ---------------------------------------------------------------------------
// fused GEMM + bias + tanh:  out = tanh((A0 [+ A1]) @ W + b)
// ---------------------------------------------------------------------------
template<int K, int C, bool TWO_IN, bool DTANH>
__global__ void gemm_act_kernel(const float* __restrict__ A0,
                                const float* __restrict__ A1,
                                const float* __restrict__ W,
                                const float* __restrict__ bias,
                                float* __restrict__ out) {
    constexpr int RB = 64;
    constexpr int KC = 32;
    constexpr int CPT = C / 16;
    __shared__ float Alds[KC][RB + 4];
    __shared__ float Wlds[KC][C];

    const int tid = threadIdx.x;
    const int ty = tid >> 4;
    const int tx = tid & 15;
    const int rb = blockIdx.x * RB;
    const int row0 = ty * 4;
    const int c0 = tx * CPT;

    float acc[4][CPT];
#pragma unroll
    for (int r = 0; r < 4; ++r)
#pragma unroll
        for (int c = 0; c < CPT; ++c) acc[r][c] = 0.f;

    for (int kc = 0; kc < K; kc += KC) {
        {
            int r = tid >> 2;
            int kq = (tid & 3) * 4;
            int grow = rb + r;
#pragma unroll
            for (int half = 0; half < 2; ++half) {
                int k0 = kq + half * 16;
                float4 v = make_float4(0.f, 0.f, 0.f, 0.f);
                if (grow < N_NODES) {
                    v = *reinterpret_cast<const float4*>(A0 + (size_t)grow * K + kc + k0);
                    if (TWO_IN) {
                        float4 u = *reinterpret_cast<const float4*>(A1 + (size_t)grow * K + kc + k0);
                        v.x += u.x; v.y += u.y; v.z += u.z; v.w += u.w;
                    }
                }
                Alds[k0 + 0][r] = v.x;
                Alds[k0 + 1][r] = v.y;
                Alds[k0 + 2][r] = v.z;
                Alds[k0 + 3][r] = v.w;
            }
        }
        {
            constexpr int PER = (KC * C) / (256 * 4);
            const float4* Wg = reinterpret_cast<const float4*>(W + (size_t)kc * C);
            float4* Wl = reinterpret_cast<float4*>(&Wlds[0][0]);
#pragma unroll
            for (int i = 0; i < PER; ++i)
                Wl[tid + i * 256] = Wg[tid + i * 256];
        }
        __syncthreads();
#pragma unroll
        for (int k = 0; k < KC; ++k) {
            float4 a = *reinterpret_cast<const float4*>(&Alds[k][row0]);
            float av[4] = {a.x, a.y, a.z, a.w};
            float w[CPT];
#pragma unroll
            for (int c = 0; c < CPT; ++c) w[c] = Wlds[k][c0 + c];
#pragma unroll
            for (int r = 0; r < 4; ++r)
#pragma unroll
                for (int c = 0; c < CPT; ++c)
                    acc[r][c] = fmaf(av[r], w[c], acc[r][c]);
        }
        __syncthreads();
    }

    float bv[CPT];
#pragma unroll
    for (int c = 0; c < CPT; ++c) bv[c] = bias[c0 + c];
#pragma unroll
    for (int r = 0; r < 4; ++r) {
        int grow = rb + row0 + r;
        if (grow >= N_NODES) continue;
#pragma unroll
        for (int c = 0; c < CPT; ++c) {
            float v = tanhf(acc[r][c] + bv[c]);
            if (DTANH) v = tanhf(v);
            out[(size_t)grow * C + c0 + c] = v;
        }
    }
}

// ---------------------------------------------------------------------------
// mean pool over sorted graph ids
// ---------------------------------------------------------------------------
__global__ void pool_mean_kernel(const float* __restrict__ x,
                                 const int* __restrict__ batch,
                                 float* __restrict__ out) {
    int g = blockIdx.x;
    int d = threadIdx.x;
    int lo = 0, hi = N_NODES;
    while (lo < hi) { int m = (lo + hi) >> 1; if (batch[m] < g) lo = m + 1; else hi = m; }
    int start = lo;
    hi = N_NODES;
    while (lo < hi) { int m = (lo + hi) >> 1; if (batch[m] < g + 1) lo = m + 1; else hi = m; }
    int end = lo;
    float s = 0.f;
    for (int i = start; i < end; ++i) s += x[(size_t)i * DIM + d];
    float cnt = (float)(end - start);
    out[g * DIM + d] = s / fmaxf(cnt, 1.f);
}

// ---------------------------------------------------------------------------
extern "C" void kernel_launch(void* const* d_in, const int* in_sizes, int n_in,
                              void* d_out, int out_size, void* d_ws, size_t ws_size,
                              hipStream_t stream) {
    const float* attrs = (const float*)d_in[0];
    const float* W1    = (const float*)d_in[1];
    const float* b1    = (const float*)d_in[2];
    const float* W2    = (const float*)d_in[3];
    const float* b2    = (const float*)d_in[4];
    const float* W3    = (const float*)d_in[5];
    const float* b3    = (const float*)d_in[6];
    const int* edge_index = (const int*)d_in[7];
    const int* batch      = (const int*)d_in[8];
    float* out = (float*)d_out;

    float* ws   = (float*)d_ws;
    float* xbuf = ws;                                   // N*D
    float* agg  = xbuf + (size_t)N_NODES * DIM;         // N*D
    float* h1   = agg  + (size_t)N_NODES * DIM;         // N*H
    float* h2   = h1   + (size_t)N_NODES * HID;         // N*H
    int* offsets = (int*)(h2 + (size_t)N_NODES * HID);  // N+1
    int* csr_src = offsets + N_NODES + 1;               // E
    // build-time scratch aliased into h1 (h1 not live until first GEMM)
    int* counts  = (int*)h1;                            // N
    int* cursor  = counts + N_NODES;                    // N
    int* bsum    = cursor + N_NODES;                    // SCAN_NB
    int* bpre    = bsum + SCAN_NB;                      // SCAN_NB

    const int* src = edge_index;
    const int* dst = edge_index + N_EDGES;

    const int gemm_blocks = (N_NODES + 63) / 64;
    const int edge_blocks = (N_EDGES + 255) / 256;
    const int gather_blocks = (N_NODES * 16 + 255) / 256;

    // ---- CSR build (once; edge list is layer-invariant) ----
    hipMemsetAsync(counts, 0, (size_t)N_NODES * sizeof(int), stream);
    count_kernel<<<edge_blocks, 256, 0, stream>>>(dst, counts);
    scan_partial_kernel<<<SCAN_NB, 256, 0, stream>>>(counts, bsum);
    scan_mid_kernel<<<1, 64, 0, stream>>>(bsum, bpre, offsets);
    scan_final_kernel<<<SCAN_NB, 256, 0, stream>>>(counts, bpre, offsets, cursor);
    place_kernel<<<edge_blocks, 256, 0, stream>>>(src, dst, cursor, csr_src);

    for (int l = 0; l < LAYERS; ++l) {
        const float* x = (l == 0) ? attrs : xbuf;
        gather_kernel<<<gather_blocks, 256, 0, stream>>>(x, offsets, csr_src, agg);
        gemm_act_kernel<DIM, HID, true, false><<<gemm_blocks, 256, 0, stream>>>(
            x, agg, W1 + (size_t)l * DIM * HID, b1 + (size_t)l * HID, h1);
        gemm_act_kernel<HID, HID, false, false><<<gemm_blocks, 256, 0, stream>>>(
            h1, nullptr, W2 + (size_t)l * HID * HID, b2 + (size_t)l * HID, h2);
        gemm_act_kernel<HID, DIM, false, true><<<gemm_blocks, 256, 0, stream>>>(
            h2, nullptr, W3 + (size_t)l * HID * DIM, b3 + (size_t)l * DIM, xbuf);
    }
    pool_mean_kernel<<<NGRAPH, DIM, 0, stream>>>(xbuf, batch, out);
}

// Round 4
// 545.305 us; speedup vs baseline: 4.5400x; 1.1328x over previous
//
#include <hip/hip_runtime.h>
#include <math.h>

#define N_NODES 50000
#define N_EDGES 800000
#define DIM 64
#define HID 128
#define LAYERS 3
#define NGRAPH 128

#define SCAN_TILE 1024
#define SCAN_NB ((N_NODES + SCAN_TILE - 1) / SCAN_TILE)   // 49

#define POOL_ROWS 256
#define POOL_NB ((N_NODES + POOL_ROWS - 1) / POOL_ROWS)   // 196

// ---------------------------------------------------------------------------
// CSR build: histogram of dst
// ---------------------------------------------------------------------------
__global__ void count_kernel(const int* __restrict__ dst, int* __restrict__ counts) {
    int e = blockIdx.x * blockDim.x + threadIdx.x;
    if (e >= N_EDGES) return;
    atomicAdd(&counts[dst[e]], 1);
}

// ---- hierarchical scan: (1) per-block reduce ----
__global__ void scan_partial_kernel(const int* __restrict__ counts,
                                    int* __restrict__ bsum) {
    __shared__ int red[256];
    const int b = blockIdx.x, tid = threadIdx.x;
    const int base = b * SCAN_TILE + tid * 4;
    int s = 0;
    if (base + 3 < N_NODES) {
        int4 v = *reinterpret_cast<const int4*>(counts + base);
        s = v.x + v.y + v.z + v.w;
    } else {
        for (int i = 0; i < 4; ++i)
            if (base + i < N_NODES) s += counts[base + i];
    }
    red[tid] = s;
    __syncthreads();
    for (int off = 128; off > 0; off >>= 1) {
        if (tid < off) red[tid] += red[tid + off];
        __syncthreads();
    }
    if (tid == 0) bsum[b] = red[0];
}

// ---- (2) scan the 49 block sums in one wave ----
__global__ void scan_mid_kernel(const int* __restrict__ bsum,
                                int* __restrict__ bpre,
                                int* __restrict__ offsets) {
    int tid = threadIdx.x;   // 64 threads, one wave
    int orig = (tid < SCAN_NB) ? bsum[tid] : 0;
    int v = orig;
    for (int off = 1; off < 64; off <<= 1) {
        int u = __shfl_up(v, off);
        if (tid >= off) v += u;
    }
    if (tid < SCAN_NB) bpre[tid] = v - orig;   // exclusive prefix
    if (tid == 0) offsets[N_NODES] = N_EDGES;
}

// ---- (3) per-block local scan + write offsets/cursor ----
__global__ void scan_final_kernel(const int* __restrict__ counts,
                                  const int* __restrict__ bpre,
                                  int* __restrict__ offsets,
                                  int* __restrict__ cursor) {
    __shared__ int pre[256];
    const int b = blockIdx.x, tid = threadIdx.x;
    const int base = b * SCAN_TILE + tid * 4;
    int c[4];
    int s = 0;
#pragma unroll
    for (int i = 0; i < 4; ++i) {
        c[i] = (base + i < N_NODES) ? counts[base + i] : 0;
        s += c[i];
    }
    pre[tid] = s;
    __syncthreads();
    for (int off = 1; off < 256; off <<= 1) {
        int v = (tid >= off) ? pre[tid - off] : 0;
        __syncthreads();
        pre[tid] += v;
        __syncthreads();
    }
    int run = bpre[b] + pre[tid] - s;   // exclusive across whole array
#pragma unroll
    for (int i = 0; i < 4; ++i) {
        if (base + i < N_NODES) {
            offsets[base + i] = run;
            cursor[base + i]  = run;
            run += c[i];
        }
    }
}

// place each edge's src into its dst's CSR slot
__global__ void place_kernel(const int* __restrict__ src,
                             const int* __restrict__ dst,
                             int* __restrict__ cursor,
                             int* __restrict__ csr_src) {
    int e = blockIdx.x * blockDim.x + threadIdx.x;
    if (e >= N_EDGES) return;
    int pos = atomicAdd(&cursor[dst[e]], 1);
    csr_src[pos] = src[e];
}

// ---------------------------------------------------------------------------
// gather aggregation: agg[i] = sum over incoming edges of x[src]
// ---------------------------------------------------------------------------
__global__ void gather_kernel(const float* __restrict__ x,
                              const int* __restrict__ offsets,
                              const int* __restrict__ csr_src,
                              float* __restrict__ agg) {
    int idx = blockIdx.x * blockDim.x + threadIdx.x;
    int node = idx >> 4;
    int lane = idx & 15;
    if (node >= N_NODES) return;
    int p   = offsets[node];
    int end = offsets[node + 1];
    float4 acc = make_float4(0.f, 0.f, 0.f, 0.f);
    for (; p < end; ++p) {
        int s = csr_src[p];
        float4 v = *reinterpret_cast<const float4*>(x + (size_t)s * DIM + lane * 4);
        acc.x += v.x; acc.y += v.y; acc.z += v.z; acc.w += v.w;
    }
    *reinterpret_cast<float4*>(agg + (size_t)node * DIM + lane * 4) = acc;
}

// ---------------------------------------------------------------------------
// fused GEMM + bias + tanh:  out = tanh((A0 [+ A1]) @ W + b)
// ---------------------------------------------------------------------------
template<int K, int C, bool TWO_IN, bool DTANH>
__global__ void gemm_act_kernel(const float* __restrict__ A0,
                                const float* __restrict__ A1,
                                const float* __restrict__ W,
                                const float* __restrict__ bias,
                                float* __restrict__ out) {
    constexpr int RB = 64;
    constexpr int KC = 32;
    constexpr int CPT = C / 16;
    __shared__ float Alds[KC][RB + 4];
    __shared__ float Wlds[KC][C];

    const int tid = threadIdx.x;
    const int ty = tid >> 4;
    const int tx = tid & 15;
    const int rb = blockIdx.x * RB;
    const int row0 = ty * 4;
    const int c0 = tx * CPT;

    float acc[4][CPT];
#pragma unroll
    for (int r = 0; r < 4; ++r)
#pragma unroll
        for (int c = 0; c < CPT; ++c) acc[r][c] = 0.f;

    for (int kc = 0; kc < K; kc += KC) {
        {
            int r = tid >> 2;
            int kq = (tid & 3) * 4;
            int grow = rb + r;
#pragma unroll
            for (int half = 0; half < 2; ++half) {
                int k0 = kq + half * 16;
                float4 v = make_float4(0.f, 0.f, 0.f, 0.f);
                if (grow < N_NODES) {
                    v = *reinterpret_cast<const float4*>(A0 + (size_t)grow * K + kc + k0);
                    if (TWO_IN) {
                        float4 u = *reinterpret_cast<const float4*>(A1 + (size_t)grow * K + kc + k0);
                        v.x += u.x; v.y += u.y; v.z += u.z; v.w += u.w;
                    }
                }
                Alds[k0 + 0][r] = v.x;
                Alds[k0 + 1][r] = v.y;
                Alds[k0 + 2][r] = v.z;
                Alds[k0 + 3][r] = v.w;
            }
        }
        {
            constexpr int PER = (KC * C) / (256 * 4);
            const float4* Wg = reinterpret_cast<const float4*>(W + (size_t)kc * C);
            float4* Wl = reinterpret_cast<float4*>(&Wlds[0][0]);
#pragma unroll
            for (int i = 0; i < PER; ++i)
                Wl[tid + i * 256] = Wg[tid + i * 256];
        }
        __syncthreads();
#pragma unroll
        for (int k = 0; k < KC; ++k) {
            float4 a = *reinterpret_cast<const float4*>(&Alds[k][row0]);
            float av[4] = {a.x, a.y, a.z, a.w};
            float w[CPT];
#pragma unroll
            for (int c = 0; c < CPT; ++c) w[c] = Wlds[k][c0 + c];
#pragma unroll
            for (int r = 0; r < 4; ++r)
#pragma unroll
                for (int c = 0; c < CPT; ++c)
                    acc[r][c] = fmaf(av[r], w[c], acc[r][c]);
        }
        __syncthreads();
    }

    float bv[CPT];
#pragma unroll
    for (int c = 0; c < CPT; ++c) bv[c] = bias[c0 + c];
#pragma unroll
    for (int r = 0; r < 4; ++r) {
        int grow = rb + row0 + r;
        if (grow >= N_NODES) continue;
#pragma unroll
        for (int c = 0; c < CPT; ++c) {
            float v = tanhf(acc[r][c] + bv[c]);
            if (DTANH) v = tanhf(v);
            out[(size_t)grow * C + c0 + c] = v;
        }
    }
}

// ---------------------------------------------------------------------------
// mean pool, node-parallel: batch is sorted, so each thread register-
// accumulates runs of equal graph id and flushes one atomicAdd per segment.
// block = 256 threads covering POOL_ROWS rows (4 rows in flight, d = tid&63)
// ---------------------------------------------------------------------------
__global__ void pool_partial_kernel(const float* __restrict__ x,
                                    const int* __restrict__ batch,
                                    float* __restrict__ sums) {
    const int tid = threadIdx.x;
    const int d = tid & 63;
    const int rg = tid >> 6;                  // 0..3
    int row = blockIdx.x * POOL_ROWS + rg;
    const int rowend = min(N_NODES, (blockIdx.x + 1) * POOL_ROWS);
    float acc = 0.f;
    int cur = -1;
    for (; row < rowend; row += 4) {
        int g = batch[row];                   // wave-uniform (64 lanes, same row)
        if (g != cur) {
            if (cur >= 0) atomicAdd(&sums[cur * DIM + d], acc);
            acc = 0.f;
            cur = g;
        }
        acc += x[(size_t)row * DIM + d];
    }
    if (cur >= 0) atomicAdd(&sums[cur * DIM + d], acc);
}

// out[g][d] = sums[g][d] / count(g); count via binary search (batch sorted)
__global__ void pool_final_kernel(const float* __restrict__ sums,
                                  const int* __restrict__ batch,
                                  float* __restrict__ out) {
    const int g = blockIdx.x;
    const int d = threadIdx.x;
    int lo = 0, hi = N_NODES;
    while (lo < hi) { int m = (lo + hi) >> 1; if (batch[m] < g) lo = m + 1; else hi = m; }
    int start = lo;
    hi = N_NODES;
    while (lo < hi) { int m = (lo + hi) >> 1; if (batch[m] < g + 1) lo = m + 1; else hi = m; }
    float cnt = (float)(lo - start);
    out[g * DIM + d] = sums[g * DIM + d] / fmaxf(cnt, 1.f);
}

// ---------------------------------------------------------------------------
extern "C" void kernel_launch(void* const* d_in, const int* in_sizes, int n_in,
                              void* d_out, int out_size, void* d_ws, size_t ws_size,
                              hipStream_t stream) {
    const float* attrs = (const float*)d_in[0];
    const float* W1    = (const float*)d_in[1];
    const float* b1    = (const float*)d_in[2];
    const float* W2    = (const float*)d_in[3];
    const float* b2    = (const float*)d_in[4];
    const float* W3    = (const float*)d_in[5];
    const float* b3    = (const float*)d_in[6];
    const int* edge_index = (const int*)d_in[7];
    const int* batch      = (const int*)d_in[8];
    float* out = (float*)d_out;

    float* ws   = (float*)d_ws;
    float* xbuf = ws;                                   // N*D
    float* agg  = xbuf + (size_t)N_NODES * DIM;         // N*D
    float* h1   = agg  + (size_t)N_NODES * DIM;         // N*H
    float* h2   = h1   + (size_t)N_NODES * HID;         // N*H
    int* offsets = (int*)(h2 + (size_t)N_NODES * HID);  // N+1
    int* csr_src = offsets + N_NODES + 1;               // E
    float* psums = (float*)(csr_src + N_EDGES);         // G*D
    // build-time scratch aliased into h1 (h1 not live until first GEMM)
    int* counts  = (int*)h1;                            // N
    int* cursor  = counts + N_NODES;                    // N
    int* bsum    = cursor + N_NODES;                    // SCAN_NB
    int* bpre    = bsum + SCAN_NB;                      // SCAN_NB

    const int* src = edge_index;
    const int* dst = edge_index + N_EDGES;

    const int gemm_blocks = (N_NODES + 63) / 64;
    const int edge_blocks = (N_EDGES + 255) / 256;
    const int gather_blocks = (N_NODES * 16 + 255) / 256;

    // ---- CSR build (once; edge list is layer-invariant) ----
    hipMemsetAsync(counts, 0, (size_t)N_NODES * sizeof(int), stream);
    count_kernel<<<edge_blocks, 256, 0, stream>>>(dst, counts);
    scan_partial_kernel<<<SCAN_NB, 256, 0, stream>>>(counts, bsum);
    scan_mid_kernel<<<1, 64, 0, stream>>>(bsum, bpre, offsets);
    scan_final_kernel<<<SCAN_NB, 256, 0, stream>>>(counts, bpre, offsets, cursor);
    place_kernel<<<edge_blocks, 256, 0, stream>>>(src, dst, cursor, csr_src);

    for (int l = 0; l < LAYERS; ++l) {
        const float* x = (l == 0) ? attrs : xbuf;
        gather_kernel<<<gather_blocks, 256, 0, stream>>>(x, offsets, csr_src, agg);
        gemm_act_kernel<DIM, HID, true, false><<<gemm_blocks, 256, 0, stream>>>(
            x, agg, W1 + (size_t)l * DIM * HID, b1 + (size_t)l * HID, h1);
        gemm_act_kernel<HID, HID, false, false><<<gemm_blocks, 256, 0, stream>>>(
            h1, nullptr, W2 + (size_t)l * HID * HID, b2 + (size_t)l * HID, h2);
        gemm_act_kernel<HID, DIM, false, true><<<gemm_blocks, 256, 0, stream>>>(
            h2, nullptr, W3 + (size_t)l * HID * DIM, b3 + (size_t)l * DIM, xbuf);
    }

    // ---- mean pool (node-parallel + tiny finalize) ----
    hipMemsetAsync(psums, 0, (size_t)NGRAPH * DIM * sizeof(float), stream);
    pool_partial_kernel<<<POOL_NB, 256, 0, stream>>>(xbuf, batch, psums);
    pool_final_kernel<<<NGRAPH, DIM, 0, stream>>>(psums, batch, out);
}

// Round 5
// 345.531 us; speedup vs baseline: 7.1649x; 1.5782x over previous
//
#include <hip/hip_runtime.h>
#include <math.h>

#define N_NODES 50000
#define N_EDGES 800000
#define DIM 64
#define HID 128
#define LAYERS 3
#define NGRAPH 128

#define SCAN_TILE 1024
#define SCAN_NB ((N_NODES + SCAN_TILE - 1) / SCAN_TILE)   // 49

#define POOL_ROWS 256
#define POOL_NB ((N_NODES + POOL_ROWS - 1) / POOL_ROWS)   // 196

typedef __attribute__((ext_vector_type(8))) short short8v;   // 8 bf16 (4 VGPR)
typedef __attribute__((ext_vector_type(4))) float f32x4;

__device__ __forceinline__ float bf2f(unsigned short u) {
    return __uint_as_float(((unsigned)u) << 16);
}
__device__ __forceinline__ unsigned short f2bf(float x) {
    unsigned u = __float_as_uint(x);
    unsigned r = (u + 0x7fff + ((u >> 16) & 1)) >> 16;   // RNE
    return (unsigned short)r;
}

// ---------------------------------------------------------------------------
// CSR build: histogram of dst
// ---------------------------------------------------------------------------
__global__ void count_kernel(const int* __restrict__ dst, int* __restrict__ counts) {
    int e = blockIdx.x * blockDim.x + threadIdx.x;
    if (e >= N_EDGES) return;
    atomicAdd(&counts[dst[e]], 1);
}

__global__ void scan_partial_kernel(const int* __restrict__ counts,
                                    int* __restrict__ bsum) {
    __shared__ int red[256];
    const int b = blockIdx.x, tid = threadIdx.x;
    const int base = b * SCAN_TILE + tid * 4;
    int s = 0;
    if (base + 3 < N_NODES) {
        int4 v = *reinterpret_cast<const int4*>(counts + base);
        s = v.x + v.y + v.z + v.w;
    } else {
        for (int i = 0; i < 4; ++i)
            if (base + i < N_NODES) s += counts[base + i];
    }
    red[tid] = s;
    __syncthreads();
    for (int off = 128; off > 0; off >>= 1) {
        if (tid < off) red[tid] += red[tid + off];
        __syncthreads();
    }
    if (tid == 0) bsum[b] = red[0];
}

__global__ void scan_mid_kernel(const int* __restrict__ bsum,
                                int* __restrict__ bpre,
                                int* __restrict__ offsets) {
    int tid = threadIdx.x;   // 64 threads, one wave
    int orig = (tid < SCAN_NB) ? bsum[tid] : 0;
    int v = orig;
    for (int off = 1; off < 64; off <<= 1) {
        int u = __shfl_up(v, off);
        if (tid >= off) v += u;
    }
    if (tid < SCAN_NB) bpre[tid] = v - orig;
    if (tid == 0) offsets[N_NODES] = N_EDGES;
}

__global__ void scan_final_kernel(const int* __restrict__ counts,
                                  const int* __restrict__ bpre,
                                  int* __restrict__ offsets,
                                  int* __restrict__ cursor) {
    __shared__ int pre[256];
    const int b = blockIdx.x, tid = threadIdx.x;
    const int base = b * SCAN_TILE + tid * 4;
    int c[4];
    int s = 0;
#pragma unroll
    for (int i = 0; i < 4; ++i) {
        c[i] = (base + i < N_NODES) ? counts[base + i] : 0;
        s += c[i];
    }
    pre[tid] = s;
    __syncthreads();
    for (int off = 1; off < 256; off <<= 1) {
        int v = (tid >= off) ? pre[tid - off] : 0;
        __syncthreads();
        pre[tid] += v;
        __syncthreads();
    }
    int run = bpre[b] + pre[tid] - s;
#pragma unroll
    for (int i = 0; i < 4; ++i) {
        if (base + i < N_NODES) {
            offsets[base + i] = run;
            cursor[base + i]  = run;
            run += c[i];
        }
    }
}

__global__ void place_kernel(const int* __restrict__ src,
                             const int* __restrict__ dst,
                             int* __restrict__ cursor,
                             int* __restrict__ csr_src) {
    int e = blockIdx.x * blockDim.x + threadIdx.x;
    if (e >= N_EDGES) return;
    int pos = atomicAdd(&cursor[dst[e]], 1);
    csr_src[pos] = src[e];
}

// ---------------------------------------------------------------------------
// weight repack: W[L][K][C] f32 -> frag-major bf16 P[L][KT][CT][64 lanes][8]
// lane l (li=l&15, hi=l>>4) gets W[kt*32 + hi*8 + j][ct*16 + li], j=0..7
// (same (hi,j)->k convention as the A-side frag loads; permutation cancels)
// ---------------------------------------------------------------------------
template<int K, int C>
__global__ void repack_kernel(const float* __restrict__ W, unsigned short* __restrict__ P) {
    constexpr int KT = K / 32, CT = C / 16;
    int t = blockIdx.x * 256 + threadIdx.x;
    if (t >= LAYERS * KT * CT * 64) return;
    int lane = t & 63; int rest = t >> 6;
    int ct = rest % CT; rest /= CT;
    int kt = rest % KT; int l = rest / KT;
    int li = lane & 15, hi = lane >> 4;
    const float* Wl = W + (size_t)l * K * C;
    short8v o;
#pragma unroll
    for (int j = 0; j < 8; ++j)
        o[j] = (short)f2bf(Wl[(size_t)(kt * 32 + hi * 8 + j) * C + ct * 16 + li]);
    *reinterpret_cast<short8v*>(P + ((size_t)l * KT * CT * 64 + (size_t)(kt * CT + ct) * 64 + lane) * 8) = o;
}

// ---------------------------------------------------------------------------
// gather: aggx[i] = bf16( x[i] + sum over incoming edges of x[src] )
// 8 lanes per node, 8 channels per lane; f32 accumulate
// ---------------------------------------------------------------------------
template<bool F32IN>
__global__ void gather_kernel(const float* __restrict__ xf,
                              const unsigned short* __restrict__ xb,
                              const int* __restrict__ offsets,
                              const int* __restrict__ csr_src,
                              unsigned short* __restrict__ aggx) {
    int idx = blockIdx.x * blockDim.x + threadIdx.x;
    int node = idx >> 3;
    int ch0 = (idx & 7) * 8;
    if (node >= N_NODES) return;
    float acc[8];
    if (F32IN) {
        const float4* p = reinterpret_cast<const float4*>(xf + (size_t)node * DIM + ch0);
        float4 a = p[0], b = p[1];
        acc[0] = a.x; acc[1] = a.y; acc[2] = a.z; acc[3] = a.w;
        acc[4] = b.x; acc[5] = b.y; acc[6] = b.z; acc[7] = b.w;
    } else {
        short8v v = *reinterpret_cast<const short8v*>(xb + (size_t)node * DIM + ch0);
#pragma unroll
        for (int j = 0; j < 8; ++j) acc[j] = bf2f((unsigned short)v[j]);
    }
    int p = offsets[node], end = offsets[node + 1];
    for (; p < end; ++p) {
        int s = csr_src[p];
        if (F32IN) {
            const float4* q = reinterpret_cast<const float4*>(xf + (size_t)s * DIM + ch0);
            float4 a = q[0], b = q[1];
            acc[0] += a.x; acc[1] += a.y; acc[2] += a.z; acc[3] += a.w;
            acc[4] += b.x; acc[5] += b.y; acc[6] += b.z; acc[7] += b.w;
        } else {
            short8v v = *reinterpret_cast<const short8v*>(xb + (size_t)s * DIM + ch0);
#pragma unroll
            for (int j = 0; j < 8; ++j) acc[j] += bf2f((unsigned short)v[j]);
        }
    }
    short8v o;
#pragma unroll
    for (int j = 0; j < 8; ++j) o[j] = (short)f2bf(acc[j]);
    *reinterpret_cast<short8v*>(aggx + (size_t)node * DIM + ch0) = o;
}

// ---------------------------------------------------------------------------
// MFMA GEMM + bias + tanh(+tanh): out = act(A @ W + b), A:[N][K] bf16
// 256 thr / 4 waves; wave owns 16 rows x C. A-frags direct from global,
// B-frags from repacked Wp. No LDS, no barriers.
// ---------------------------------------------------------------------------
template<int K, int C, bool DTANH>
__global__ __launch_bounds__(256) void gemm_mfma_kernel(const unsigned short* __restrict__ A,
                                                        const unsigned short* __restrict__ Wp,
                                                        const float* __restrict__ bias,
                                                        unsigned short* __restrict__ out) {
    constexpr int KT = K / 32, CT = C / 16;
    const int tid = threadIdx.x;
    const int wave = tid >> 6, lane = tid & 63;
    const int li = lane & 15, hi = lane >> 4;
    const int r0 = blockIdx.x * 64 + wave * 16;

    int ar = r0 + li;
    if (ar >= N_NODES) ar = N_NODES - 1;   // clamped read; store is guarded

    short8v af[KT];
#pragma unroll
    for (int kt = 0; kt < KT; ++kt)
        af[kt] = *reinterpret_cast<const short8v*>(A + (size_t)ar * K + kt * 32 + hi * 8);

    f32x4 acc[CT];
#pragma unroll
    for (int ct = 0; ct < CT; ++ct) acc[ct] = (f32x4){0.f, 0.f, 0.f, 0.f};

#pragma unroll
    for (int ct = 0; ct < CT; ++ct) {
#pragma unroll
        for (int kt = 0; kt < KT; ++kt) {
            short8v bf = *reinterpret_cast<const short8v*>(Wp + ((size_t)(kt * CT + ct) * 64 + lane) * 8);
            acc[ct] = __builtin_amdgcn_mfma_f32_16x16x32_bf16(af[kt], bf, acc[ct], 0, 0, 0);
        }
    }

#pragma unroll
    for (int ct = 0; ct < CT; ++ct) {
        float bv = bias[ct * 16 + li];
#pragma unroll
        for (int j = 0; j < 4; ++j) {
            int r = r0 + hi * 4 + j;          // C/D: col=lane&15, row=(lane>>4)*4+reg
            if (r >= N_NODES) continue;
            float v = tanhf(acc[ct][j] + bv);
            if (DTANH) v = tanhf(v);
            out[(size_t)r * C + ct * 16 + li] = f2bf(v);
        }
    }
}

// ---------------------------------------------------------------------------
// mean pool (node-parallel, bf16 input) + finalize
// ---------------------------------------------------------------------------
__global__ void pool_partial_kernel(const unsigned short* __restrict__ x,
                                    const int* __restrict__ batch,
                                    float* __restrict__ sums) {
    const int tid = threadIdx.x;
    const int d = tid & 63;
    const int rg = tid >> 6;
    int row = blockIdx.x * POOL_ROWS + rg;
    const int rowend = min(N_NODES, (blockIdx.x + 1) * POOL_ROWS);
    float acc = 0.f;
    int cur = -1;
    for (; row < rowend; row += 4) {
        int g = batch[row];
        if (g != cur) {
            if (cur >= 0) atomicAdd(&sums[cur * DIM + d], acc);
            acc = 0.f;
            cur = g;
        }
        acc += bf2f(x[(size_t)row * DIM + d]);
    }
    if (cur >= 0) atomicAdd(&sums[cur * DIM + d], acc);
}

__global__ void pool_final_kernel(const float* __restrict__ sums,
                                  const int* __restrict__ batch,
                                  float* __restrict__ out) {
    const int g = blockIdx.x;
    const int d = threadIdx.x;
    int lo = 0, hi = N_NODES;
    while (lo < hi) { int m = (lo + hi) >> 1; if (batch[m] < g) lo = m + 1; else hi = m; }
    int start = lo;
    hi = N_NODES;
    while (lo < hi) { int m = (lo + hi) >> 1; if (batch[m] < g + 1) lo = m + 1; else hi = m; }
    float cnt = (float)(lo - start);
    out[g * DIM + d] = sums[g * DIM + d] / fmaxf(cnt, 1.f);
}

// ---------------------------------------------------------------------------
extern "C" void kernel_launch(void* const* d_in, const int* in_sizes, int n_in,
                              void* d_out, int out_size, void* d_ws, size_t ws_size,
                              hipStream_t stream) {
    const float* attrs = (const float*)d_in[0];
    const float* W1    = (const float*)d_in[1];
    const float* b1    = (const float*)d_in[2];
    const float* W2    = (const float*)d_in[3];
    const float* b2    = (const float*)d_in[4];
    const float* W3    = (const float*)d_in[5];
    const float* b3    = (const float*)d_in[6];
    const int* edge_index = (const int*)d_in[7];
    const int* batch      = (const int*)d_in[8];
    float* out = (float*)d_out;

    unsigned short* xbuf = (unsigned short*)d_ws;               // N*64 bf16
    unsigned short* aggx = xbuf + (size_t)N_NODES * DIM;        // N*64 bf16
    unsigned short* h1   = aggx + (size_t)N_NODES * DIM;        // N*128 bf16
    unsigned short* h2   = h1 + (size_t)N_NODES * HID;          // N*128 bf16
    unsigned short* pW1  = h2 + (size_t)N_NODES * HID;          // 3*2*8*64*8 = 24576
    unsigned short* pW2  = pW1 + 24576;                         // 3*4*8*64*8 = 49152
    unsigned short* pW3  = pW2 + 49152;                         // 3*4*4*64*8 = 24576
    float* psums  = (float*)(pW3 + 24576);                      // G*64 f32
    int* offsets  = (int*)(psums + NGRAPH * DIM);               // N+1
    int* csr_src  = offsets + N_NODES + 1;                      // E
    // CSR-build scratch aliased into h1 (h1 not live until first GEMM)
    int* counts = (int*)h1;                                     // N
    int* cursor = counts + N_NODES;                             // N
    int* bsum   = cursor + N_NODES;                             // SCAN_NB
    int* bpre   = bsum + SCAN_NB;                               // SCAN_NB

    const int* src = edge_index;
    const int* dst = edge_index + N_EDGES;

    const int gemm_blocks = (N_NODES + 63) / 64;                // 782
    const int edge_blocks = (N_EDGES + 255) / 256;
    const int gather_blocks = (N_NODES * 8 + 255) / 256;

    // ---- CSR build (once; edge list is layer-invariant) ----
    hipMemsetAsync(counts, 0, (size_t)N_NODES * sizeof(int), stream);
    count_kernel<<<edge_blocks, 256, 0, stream>>>(dst, counts);
    scan_partial_kernel<<<SCAN_NB, 256, 0, stream>>>(counts, bsum);
    scan_mid_kernel<<<1, 64, 0, stream>>>(bsum, bpre, offsets);
    scan_final_kernel<<<SCAN_NB, 256, 0, stream>>>(counts, bpre, offsets, cursor);
    place_kernel<<<edge_blocks, 256, 0, stream>>>(src, dst, cursor, csr_src);

    // ---- weight repack to frag-major bf16 (once) ----
    repack_kernel<DIM, HID><<<(LAYERS * 2 * 8 * 64 + 255) / 256, 256, 0, stream>>>(W1, pW1);
    repack_kernel<HID, HID><<<(LAYERS * 4 * 8 * 64 + 255) / 256, 256, 0, stream>>>(W2, pW2);
    repack_kernel<HID, DIM><<<(LAYERS * 4 * 4 * 64 + 255) / 256, 256, 0, stream>>>(W3, pW3);

    for (int l = 0; l < LAYERS; ++l) {
        if (l == 0)
            gather_kernel<true><<<gather_blocks, 256, 0, stream>>>(attrs, nullptr, offsets, csr_src, aggx);
        else
            gather_kernel<false><<<gather_blocks, 256, 0, stream>>>(nullptr, xbuf, offsets, csr_src, aggx);
        gemm_mfma_kernel<DIM, HID, false><<<gemm_blocks, 256, 0, stream>>>(
            aggx, pW1 + (size_t)l * 2 * 8 * 64 * 8, b1 + (size_t)l * HID, h1);
        gemm_mfma_kernel<HID, HID, false><<<gemm_blocks, 256, 0, stream>>>(
            h1, pW2 + (size_t)l * 4 * 8 * 64 * 8, b2 + (size_t)l * HID, h2);
        gemm_mfma_kernel<HID, DIM, true><<<gemm_blocks, 256, 0, stream>>>(
            h2, pW3 + (size_t)l * 4 * 4 * 64 * 8, b3 + (size_t)l * DIM, xbuf);
    }

    // ---- mean pool ----
    hipMemsetAsync(psums, 0, (size_t)NGRAPH * DIM * sizeof(float), stream);
    pool_partial_kernel<<<POOL_NB, 256, 0, stream>>>(xbuf, batch, psums);
    pool_final_kernel<<<NGRAPH, DIM, 0, stream>>>(psums, batch, out);
}